// Round 5
// baseline (1849.911 us; speedup 1.0000x reference)
//
#include <hip/hip_runtime.h>
#include <math.h>

#define N_NODES 100000
#define N_EDGES 1000000
#define IN_F 128
#define H_F 64
#define THRV 0.1f
#define LN_EPS 1e-5f
#define GRID_AGG 2048

#define BSHIFT 9                 // 512 nodes per bucket
#define NB 196                   // ceil(100000 / 512)
#define EPB 2048                 // edges per partition block
#define NPB ((N_EDGES + EPB - 1) / EPB)  // 489

static __device__ __forceinline__ float wave_sum(float x) {
  for (int o = 32; o > 0; o >>= 1) x += __shfl_xor(x, o, 64);
  return x;
}
static __device__ __forceinline__ float wave_max(float x) {
  for (int o = 32; o > 0; o >>= 1) x = fmaxf(x, __shfl_xor(x, o, 64));
  return x;
}

// ---- CSR build via bucket partition (no random global scatter) ----

__global__ __launch_bounds__(256) void k_bcount(const int* __restrict__ dst,
                                                int* __restrict__ bcnt) {
  __shared__ int h[NB];
  for (int i = threadIdx.x; i < NB; i += 256) h[i] = 0;
  __syncthreads();
  int base = blockIdx.x * EPB;
  for (int i = threadIdx.x; i < EPB; i += 256) {
    int e = base + i;
    if (e < N_EDGES) atomicAdd(&h[dst[e] >> BSHIFT], 1);
  }
  __syncthreads();
  for (int i = threadIdx.x; i < NB; i += 256)
    if (h[i]) atomicAdd(&bcnt[i], h[i]);
}

__global__ void k_bscan(const int* __restrict__ bcnt, int* __restrict__ bbase,
                        int* __restrict__ bcur) {
  __shared__ int lds[256];
  int t = threadIdx.x;
  int v = (t < NB) ? bcnt[t] : 0;
  lds[t] = v;
  __syncthreads();
  int val = v;
  for (int o = 1; o < 256; o <<= 1) {
    int y = (t >= o) ? lds[t - o] : 0;
    __syncthreads();
    val += y;
    lds[t] = val;
    __syncthreads();
  }
  if (t < NB) {
    int ex = val - v;
    bbase[t] = ex;
    bcur[t] = ex;
  }
  if (t == 255) bbase[NB] = val;  // total
}

// Partition edges into bucket-contiguous regions as packed records:
// rec = src | (dstLocal << 17)   (src < 2^17, dstLocal < 2^9)
__global__ __launch_bounds__(256) void k_part(const int* __restrict__ src,
                                              const int* __restrict__ dst,
                                              int* __restrict__ bcur,
                                              int* __restrict__ part) {
  __shared__ int h[NB];
  __shared__ int cur[NB];
  for (int i = threadIdx.x; i < NB; i += 256) h[i] = 0;
  __syncthreads();
  int base = blockIdx.x * EPB;
  for (int i = threadIdx.x; i < EPB; i += 256) {
    int e = base + i;
    if (e < N_EDGES) atomicAdd(&h[dst[e] >> BSHIFT], 1);
  }
  __syncthreads();
  for (int i = threadIdx.x; i < NB; i += 256) {
    int c = h[i];
    cur[i] = c ? atomicAdd(&bcur[i], c) : 0;
  }
  __syncthreads();
  for (int i = threadIdx.x; i < EPB; i += 256) {
    int e = base + i;
    if (e < N_EDGES) {
      int d = dst[e];
      int b = d >> BSHIFT;
      int pos = atomicAdd(&cur[b], 1);
      part[pos] = src[e] | ((d & 511) << 17);
    }
  }
}

// One block per bucket: count per-node degrees in LDS, scan, emit
// indeg/offs/dis1 (coalesced) and csr_src (scatter within L2-resident region).
__global__ __launch_bounds__(256) void k_build(
    const int* __restrict__ part, const int* __restrict__ bbase,
    int* __restrict__ indeg, int* __restrict__ offs, float* __restrict__ dis1,
    int* __restrict__ csr_src) {
  __shared__ int cnt[512];
  __shared__ int slds[256];
  int b = blockIdx.x;
  int t = threadIdx.x;
  int beg = bbase[b], end = bbase[b + 1];
  for (int i = t; i < 512; i += 256) cnt[i] = 0;
  __syncthreads();
  for (int i = beg + t; i < end; i += 256)
    atomicAdd(&cnt[(part[i] >> 17) & 511], 1);
  __syncthreads();
  int a0 = cnt[2 * t], a1 = cnt[2 * t + 1];
  int pairsum = a0 + a1;
  slds[t] = pairsum;
  __syncthreads();
  int val = pairsum;
  for (int o = 1; o < 256; o <<= 1) {
    int y = (t >= o) ? slds[t - o] : 0;
    __syncthreads();
    val += y;
    slds[t] = val;
    __syncthreads();
  }
  int ex = val - pairsum;  // exclusive over this thread's pair
  int off0 = ex, off1 = ex + a0;
  cnt[2 * t] = off0;  // reuse as scatter cursors
  cnt[2 * t + 1] = off1;
  int node0 = (b << BSHIFT) + 2 * t;
  if (node0 < N_NODES) {
    indeg[node0] = a0;
    offs[node0] = beg + off0;
    dis1[node0] = rsqrtf((float)a0 + 1.f);
  }
  if (node0 + 1 < N_NODES) {
    indeg[node0 + 1] = a1;
    offs[node0 + 1] = beg + off1;
    dis1[node0 + 1] = rsqrtf((float)a1 + 1.f);
  }
  __syncthreads();
  for (int i = beg + t; i < end; i += 256) {
    int p = part[i];
    int loc = (p >> 17) & 511;
    int pos = atomicAdd(&cnt[loc], 1);
    csr_src[beg + pos] = p & 131071;
  }
}

// K-chunked double-buffered tile GEMM: Y[r][64] = (X[r][K] @ W[K][64]) * scale[r].
// Block computes a 64x64 tile; K in chunks of 32 with 2-deep LDS double buffer
// (32 KB total -> 4 blocks/CU). Per chunk: issue next-chunk global loads early,
// compute current, ds_write late, one barrier.
template <int K>
__global__ __launch_bounds__(256, 4) void k_gemm(const float* __restrict__ X,
                                                 const float* __restrict__ W,
                                                 const float* __restrict__ scale,
                                                 float* __restrict__ Y, int nrows) {
  constexpr int KC = 32;
  constexpr int NCH = K / KC;
  __shared__ __align__(16) float Xs[2][64][KC];
  __shared__ __align__(16) float Ws[2][KC][64];
  int t = threadIdx.x;
  int rbase = blockIdx.x * 64;

  // staging coords: X -> thread loads rows srow, srow+32; 16B chunk sc4
  int srow = t >> 3;  // 0..31
  int sc4 = t & 7;    // 0..7
  int g0 = rbase + srow;
  int g1 = rbase + srow + 32;
  if (g0 >= nrows) g0 = nrows - 1;
  if (g1 >= nrows) g1 = nrows - 1;
  const float* xp0 = X + (size_t)g0 * K + sc4 * 4;
  const float* xp1 = X + (size_t)g1 * K + sc4 * 4;
  int xsw = (sc4 ^ (srow & 7)) * 4;  // swizzled chunk offset (srow+32 same: 32%8==0)
  // W -> thread loads rows wk, wk+16; col group wc
  int wk = t >> 4;  // 0..15
  int wc = t & 15;  // 0..15
  const float* wp0 = W + wk * 64 + wc * 4;
  const float* wp1 = W + (wk + 16) * 64 + wc * 4;

  // stage chunk 0
  {
    float4 xa = *(const float4*)xp0;
    float4 xb = *(const float4*)xp1;
    float4 wa = *(const float4*)wp0;
    float4 wb = *(const float4*)wp1;
    *(float4*)&Xs[0][srow][xsw] = xa;
    *(float4*)&Xs[0][srow + 32][xsw] = xb;
    *(float4*)&Ws[0][wk][wc * 4] = wa;
    *(float4*)&Ws[0][wk + 16][wc * 4] = wb;
  }
  __syncthreads();

  int tx = t & 15, ty = t >> 4;
  int r0 = ty * 4, c0 = tx * 4;
  float acc[4][4] = {};

#pragma unroll
  for (int c = 0; c < NCH; ++c) {
    int cur = c & 1;
    float4 nxa, nxb, nwa, nwb;
    if (c + 1 < NCH) {  // issue next-chunk loads early
      nxa = *(const float4*)(xp0 + (c + 1) * KC);
      nxb = *(const float4*)(xp1 + (c + 1) * KC);
      nwa = *(const float4*)(wp0 + (c + 1) * KC * 64);
      nwb = *(const float4*)(wp1 + (c + 1) * KC * 64);
    }
#pragma unroll
    for (int k = 0; k < KC; k += 4) {
      float xv[4][4], wv[4][4];
#pragma unroll
      for (int i = 0; i < 4; ++i) {
        int r = r0 + i;
        *(float4*)xv[i] = *(const float4*)&Xs[cur][r][(((k >> 2) ^ (r & 7))) * 4];
      }
#pragma unroll
      for (int j = 0; j < 4; ++j)
        *(float4*)wv[j] = *(const float4*)&Ws[cur][k + j][c0];
#pragma unroll
      for (int i = 0; i < 4; ++i)
#pragma unroll
        for (int kk = 0; kk < 4; ++kk)
#pragma unroll
          for (int j = 0; j < 4; ++j)
            acc[i][j] = fmaf(xv[i][kk], wv[kk][j], acc[i][j]);
    }
    if (c + 1 < NCH) {  // write next chunk late
      int nxt = cur ^ 1;
      *(float4*)&Xs[nxt][srow][xsw] = nxa;
      *(float4*)&Xs[nxt][srow + 32][xsw] = nxb;
      *(float4*)&Ws[nxt][wk][wc * 4] = nwa;
      *(float4*)&Ws[nxt][wk + 16][wc * 4] = nwb;
      __syncthreads();
    }
  }

#pragma unroll
  for (int i = 0; i < 4; ++i) {
    int gr = rbase + r0 + i;
    if (gr < nrows) {
      float sc = scale[gr];
      float4 o;
      o.x = acc[i][0] * sc;
      o.y = acc[i][1] * sc;
      o.z = acc[i][2] * sc;
      o.w = acc[i][3] * sc;
      *(float4*)(Y + (size_t)gr * 64 + c0) = o;
    }
  }
}

// Layer-0 aggregation over prescaled rows h1p (= h1 * dis1), fused with +b1,
// LayerNorm, ReLU, score s[v], block min/max partials.
__global__ __launch_bounds__(256) void k_agg1(
    const float* __restrict__ h1p, const int* __restrict__ offs,
    const int* __restrict__ indeg, const int* __restrict__ csr_src,
    const float* __restrict__ dis1, const float* __restrict__ b1,
    const float* __restrict__ gamma, const float* __restrict__ beta,
    float* __restrict__ h, float* __restrict__ s, float* __restrict__ mmpart) {
  int lane = threadIdx.x & 63;
  int wid = blockIdx.x * 4 + (threadIdx.x >> 6);
  int nw = gridDim.x * 4;
  float bmin = __builtin_inff(), bmax = -__builtin_inff();
  for (int v = wid; v < N_NODES; v += nw) {
    int beg = offs[v];
    int deg = indeg[v];
    float disv = dis1[v];
    float acc = h1p[v * 64 + lane];  // self-loop term (prescaled)
    for (int c = 0; c < deg; c += 64) {
      int m = deg - c;
      if (m > 64) m = 64;
      int ul = (lane < m) ? csr_src[beg + c + lane] : 0;
      int j = 0;
      for (; j + 8 <= m; j += 8) {
        int u0 = __shfl(ul, j + 0), u1 = __shfl(ul, j + 1);
        int u2 = __shfl(ul, j + 2), u3 = __shfl(ul, j + 3);
        int u4 = __shfl(ul, j + 4), u5 = __shfl(ul, j + 5);
        int u6 = __shfl(ul, j + 6), u7 = __shfl(ul, j + 7);
        float a0 = h1p[u0 * 64 + lane], a1 = h1p[u1 * 64 + lane];
        float a2 = h1p[u2 * 64 + lane], a3 = h1p[u3 * 64 + lane];
        float a4 = h1p[u4 * 64 + lane], a5 = h1p[u5 * 64 + lane];
        float a6 = h1p[u6 * 64 + lane], a7 = h1p[u7 * 64 + lane];
        acc += ((a0 + a1) + (a2 + a3)) + ((a4 + a5) + (a6 + a7));
      }
      for (; j < m; ++j) {
        int u = __shfl(ul, j);
        acc += h1p[u * 64 + lane];
      }
    }
    acc = disv * acc + b1[lane];
    float mu = wave_sum(acc) * (1.f / 64.f);
    float d = acc - mu;
    float var = wave_sum(d * d) * (1.f / 64.f);
    float hn = d * rsqrtf(var + LN_EPS) * gamma[lane] + beta[lane];
    hn = fmaxf(hn, 0.f);
    h[v * 64 + lane] = hn;
    float sv = sqrtf(wave_sum(hn * hn));  // wave-uniform
    if (lane == 0) s[v] = sv;
    bmin = fminf(bmin, sv);
    bmax = fmaxf(bmax, sv);
  }
  __shared__ float lmin[4], lmax[4];
  if ((threadIdx.x & 63) == 0) {
    lmin[threadIdx.x >> 6] = bmin;
    lmax[threadIdx.x >> 6] = bmax;
  }
  __syncthreads();
  if (threadIdx.x == 0) {
    mmpart[blockIdx.x * 2] = fminf(fminf(lmin[0], lmin[1]), fminf(lmin[2], lmin[3]));
    mmpart[blockIdx.x * 2 + 1] = fmaxf(fmaxf(lmax[0], lmax[1]), fmaxf(lmax[2], lmax[3]));
  }
}

__global__ void k_minmax2(const float* __restrict__ mmpart, float* __restrict__ smm,
                          int nblk) {
  int t = threadIdx.x;  // 256
  float mn = __builtin_inff(), mx = -__builtin_inff();
  for (int i = t; i < nblk; i += 256) {
    mn = fminf(mn, mmpart[i * 2]);
    mx = fmaxf(mx, mmpart[i * 2 + 1]);
  }
  for (int o = 32; o; o >>= 1) {
    mn = fminf(mn, __shfl_xor(mn, o, 64));
    mx = fmaxf(mx, __shfl_xor(mx, o, 64));
  }
  __shared__ float a[4], b[4];
  if ((t & 63) == 0) { a[t >> 6] = mn; b[t >> 6] = mx; }
  __syncthreads();
  if (t == 0) {
    smm[0] = fminf(fminf(a[0], a[1]), fminf(a[2], a[3]));
    smm[1] = fmaxf(fmaxf(b[0], b[1]), fmaxf(b[2], b[3]));
  }
}

__global__ void k_dis2(const float* __restrict__ s, const float* __restrict__ smm,
                       const int* __restrict__ indeg, float* __restrict__ dis2) {
  int v = blockIdx.x * blockDim.x + threadIdx.x;
  if (v < N_NODES) {
    float inv = 1.f / (smm[1] - smm[0] + 1e-8f);
    float sn = (s[v] - smm[0]) * inv;
    float d = (sn > THRV) ? (float)indeg[v] : 0.f;
    dis2[v] = rsqrtf(d + 1.f);
  }
}

// Layer-1 masked aggregation over prescaled rows h2p (= h2 * dis2), fused with
// +b2 and log_softmax into d_out.
__global__ __launch_bounds__(256) void k_agg2(
    const float* __restrict__ h2p, const int* __restrict__ offs,
    const int* __restrict__ indeg, const int* __restrict__ csr_src,
    const float* __restrict__ s, const float* __restrict__ smm,
    const float* __restrict__ dis2, const float* __restrict__ b2,
    float* __restrict__ out) {
  int lane = threadIdx.x & 63;
  int wid = blockIdx.x * 4 + (threadIdx.x >> 6);
  int nw = gridDim.x * 4;
  float smin = smm[0];
  float inv = 1.f / (smm[1] - smm[0] + 1e-8f);
  for (int v = wid; v < N_NODES; v += nw) {
    float disv = dis2[v];
    float sn = (s[v] - smin) * inv;
    float acc = h2p[v * 64 + lane];  // self-loop term (prescaled)
    if (sn > THRV) {
      int beg = offs[v];
      int deg = indeg[v];
      for (int c = 0; c < deg; c += 64) {
        int m = deg - c;
        if (m > 64) m = 64;
        int ul = (lane < m) ? csr_src[beg + c + lane] : 0;
        int j = 0;
        for (; j + 8 <= m; j += 8) {
          int u0 = __shfl(ul, j + 0), u1 = __shfl(ul, j + 1);
          int u2 = __shfl(ul, j + 2), u3 = __shfl(ul, j + 3);
          int u4 = __shfl(ul, j + 4), u5 = __shfl(ul, j + 5);
          int u6 = __shfl(ul, j + 6), u7 = __shfl(ul, j + 7);
          float a0 = h2p[u0 * 64 + lane], a1 = h2p[u1 * 64 + lane];
          float a2 = h2p[u2 * 64 + lane], a3 = h2p[u3 * 64 + lane];
          float a4 = h2p[u4 * 64 + lane], a5 = h2p[u5 * 64 + lane];
          float a6 = h2p[u6 * 64 + lane], a7 = h2p[u7 * 64 + lane];
          acc += ((a0 + a1) + (a2 + a3)) + ((a4 + a5) + (a6 + a7));
        }
        for (; j < m; ++j) {
          int u = __shfl(ul, j);
          acc += h2p[u * 64 + lane];
        }
      }
    }
    acc = disv * acc + b2[lane];
    float m = wave_max(acc);
    float p = expf(acc - m);
    float sum = wave_sum(p);
    out[v * 64 + lane] = acc - m - logf(sum);
  }
}

extern "C" void kernel_launch(void* const* d_in, const int* in_sizes, int n_in,
                              void* d_out, int out_size, void* d_ws, size_t ws_size,
                              hipStream_t stream) {
  const float* x = (const float*)d_in[0];
  const float* W1 = (const float*)d_in[1];
  const float* b1 = (const float*)d_in[2];
  const float* W2 = (const float*)d_in[3];
  const float* b2 = (const float*)d_in[4];
  const float* gamma = (const float*)d_in[5];
  const float* beta = (const float*)d_in[6];
  const int* ei = (const int*)d_in[7];
  const int* src = ei;
  const int* dst = ei + N_EDGES;
  float* out = (float*)d_out;

  char* ws = (char*)d_ws;
  size_t off = 0;
  auto alloc = [&](size_t bytes) {
    void* p = ws + off;
    off += (bytes + 255) & ~(size_t)255;
    return p;
  };
  int* indeg = (int*)alloc(N_NODES * 4);
  int* offs = (int*)alloc(N_NODES * 4);
  int* bcnt = (int*)alloc(NB * 4);
  int* bbase = (int*)alloc((NB + 1) * 4);
  int* bcur = (int*)alloc(NB * 4);
  int* csr_src = (int*)alloc(N_EDGES * 4);
  float* s = (float*)alloc(N_NODES * 4);
  float* dis1 = (float*)alloc(N_NODES * 4);
  float* dis2 = (float*)alloc(N_NODES * 4);
  float* mmpart = (float*)alloc(GRID_AGG * 2 * 4);
  float* smm = (float*)alloc(256);
  float* h1 = (float*)alloc((size_t)N_NODES * 64 * 4);
  float* h = (float*)alloc((size_t)N_NODES * 64 * 4);
  int* part = (int*)h1;  // alias: part is dead before gemm1 writes h1
  (void)ws_size;
  (void)n_in;
  (void)in_sizes;
  (void)out_size;

  hipMemsetAsync(bcnt, 0, NB * 4, stream);
  k_bcount<<<NPB, 256, 0, stream>>>(dst, bcnt);
  k_bscan<<<1, 256, 0, stream>>>(bcnt, bbase, bcur);
  k_part<<<NPB, 256, 0, stream>>>(src, dst, bcur, part);
  k_build<<<NB, 256, 0, stream>>>(part, bbase, indeg, offs, dis1, csr_src);
  int gemm_grid = (N_NODES + 63) / 64;  // 1563
  k_gemm<IN_F><<<gemm_grid, 256, 0, stream>>>(x, W1, dis1, h1, N_NODES);
  k_agg1<<<GRID_AGG, 256, 0, stream>>>(h1, offs, indeg, csr_src, dis1, b1, gamma,
                                       beta, h, s, mmpart);
  k_minmax2<<<1, 256, 0, stream>>>(mmpart, smm, GRID_AGG);
  k_dis2<<<(N_NODES + 255) / 256, 256, 0, stream>>>(s, smm, indeg, dis2);
  k_gemm<H_F><<<gemm_grid, 256, 0, stream>>>(h, W2, dis2, h1 /* reuse as h2p */, N_NODES);
  k_agg2<<<GRID_AGG, 256, 0, stream>>>(h1, offs, indeg, csr_src, s, smm, dis2, b2,
                                       out);
}

// Round 6
// 238.989 us; speedup vs baseline: 7.7406x; 7.7406x over previous
//
#include <hip/hip_runtime.h>
#include <math.h>

#define N_NODES 100000
#define N_EDGES 1000000
#define IN_F 128
#define H_F 64
#define THRV 0.1f
#define LN_EPS 1e-5f
#define GRID_AGG 2048

#define BSHIFT 9                 // 512 nodes per bucket
#define NB 196                   // ceil(100000 / 512)
#define EPB 2048                 // edges per partition block
#define NPB ((N_EDGES + EPB - 1) / EPB)  // 489

static __device__ __forceinline__ float wave_sum(float x) {
  for (int o = 32; o > 0; o >>= 1) x += __shfl_xor(x, o, 64);
  return x;
}
static __device__ __forceinline__ float wave_max(float x) {
  for (int o = 32; o > 0; o >>= 1) x = fmaxf(x, __shfl_xor(x, o, 64));
  return x;
}

// async global->LDS, 16B per lane; lds base must be wave-uniform.
static __device__ __forceinline__ void async16(const void* g, void* l) {
  __builtin_amdgcn_global_load_lds(
      (const __attribute__((address_space(1))) void*)g,
      (__attribute__((address_space(3))) void*)l, 16, 0, 0);
}

// ---- CSR build via bucket partition (no random global scatter) ----

__global__ __launch_bounds__(256) void k_bcount(const int* __restrict__ dst,
                                                int* __restrict__ bcnt) {
  __shared__ int h[NB];
  for (int i = threadIdx.x; i < NB; i += 256) h[i] = 0;
  __syncthreads();
  int base = blockIdx.x * EPB;
  for (int i = threadIdx.x; i < EPB; i += 256) {
    int e = base + i;
    if (e < N_EDGES) atomicAdd(&h[dst[e] >> BSHIFT], 1);
  }
  __syncthreads();
  for (int i = threadIdx.x; i < NB; i += 256)
    if (h[i]) atomicAdd(&bcnt[i], h[i]);
}

__global__ void k_bscan(const int* __restrict__ bcnt, int* __restrict__ bbase,
                        int* __restrict__ bcur) {
  __shared__ int lds[256];
  int t = threadIdx.x;
  int v = (t < NB) ? bcnt[t] : 0;
  lds[t] = v;
  __syncthreads();
  int val = v;
  for (int o = 1; o < 256; o <<= 1) {
    int y = (t >= o) ? lds[t - o] : 0;
    __syncthreads();
    val += y;
    lds[t] = val;
    __syncthreads();
  }
  if (t < NB) {
    int ex = val - v;
    bbase[t] = ex;
    bcur[t] = ex;
  }
  if (t == 255) bbase[NB] = val;  // total
}

// Partition edges into bucket-contiguous regions as packed records:
// rec = src | (dstLocal << 17)   (src < 2^17, dstLocal < 2^9)
__global__ __launch_bounds__(256) void k_part(const int* __restrict__ src,
                                              const int* __restrict__ dst,
                                              int* __restrict__ bcur,
                                              int* __restrict__ part) {
  __shared__ int h[NB];
  __shared__ int cur[NB];
  for (int i = threadIdx.x; i < NB; i += 256) h[i] = 0;
  __syncthreads();
  int base = blockIdx.x * EPB;
  for (int i = threadIdx.x; i < EPB; i += 256) {
    int e = base + i;
    if (e < N_EDGES) atomicAdd(&h[dst[e] >> BSHIFT], 1);
  }
  __syncthreads();
  for (int i = threadIdx.x; i < NB; i += 256) {
    int c = h[i];
    cur[i] = c ? atomicAdd(&bcur[i], c) : 0;
  }
  __syncthreads();
  for (int i = threadIdx.x; i < EPB; i += 256) {
    int e = base + i;
    if (e < N_EDGES) {
      int d = dst[e];
      int b = d >> BSHIFT;
      int pos = atomicAdd(&cur[b], 1);
      part[pos] = src[e] | ((d & 511) << 17);
    }
  }
}

// One block per bucket: count per-node degrees in LDS, scan, emit
// indeg/offs/dis1 (coalesced) and csr_src (scatter within L2-resident region).
__global__ __launch_bounds__(256) void k_build(
    const int* __restrict__ part, const int* __restrict__ bbase,
    int* __restrict__ indeg, int* __restrict__ offs, float* __restrict__ dis1,
    int* __restrict__ csr_src) {
  __shared__ int cnt[512];
  __shared__ int slds[256];
  int b = blockIdx.x;
  int t = threadIdx.x;
  int beg = bbase[b], end = bbase[b + 1];
  for (int i = t; i < 512; i += 256) cnt[i] = 0;
  __syncthreads();
  for (int i = beg + t; i < end; i += 256)
    atomicAdd(&cnt[(part[i] >> 17) & 511], 1);
  __syncthreads();
  int a0 = cnt[2 * t], a1 = cnt[2 * t + 1];
  int pairsum = a0 + a1;
  slds[t] = pairsum;
  __syncthreads();
  int val = pairsum;
  for (int o = 1; o < 256; o <<= 1) {
    int y = (t >= o) ? slds[t - o] : 0;
    __syncthreads();
    val += y;
    slds[t] = val;
    __syncthreads();
  }
  int ex = val - pairsum;  // exclusive over this thread's pair
  int off0 = ex, off1 = ex + a0;
  cnt[2 * t] = off0;  // reuse as scatter cursors
  cnt[2 * t + 1] = off1;
  int node0 = (b << BSHIFT) + 2 * t;
  if (node0 < N_NODES) {
    indeg[node0] = a0;
    offs[node0] = beg + off0;
    dis1[node0] = rsqrtf((float)a0 + 1.f);
  }
  if (node0 + 1 < N_NODES) {
    indeg[node0 + 1] = a1;
    offs[node0 + 1] = beg + off1;
    dis1[node0 + 1] = rsqrtf((float)a1 + 1.f);
  }
  __syncthreads();
  for (int i = beg + t; i < end; i += 256) {
    int p = part[i];
    int loc = (p >> 17) & 511;
    int pos = atomicAdd(&cnt[loc], 1);
    csr_src[beg + pos] = p & 131071;
  }
}

// K-chunked double-buffered tile GEMM via global_load_lds (no VGPR staging):
// Y[r][64] = (X[r][K] @ W[K][64]) * scale[r]. Block = 64x64 tile, KC=32,
// 2-deep LDS double buffer (32 KB). X swizzle applied on the GLOBAL source
// address (LDS dest must be linear for global_load_lds); reads use the same
// XOR -> <=2-way bank conflicts (free).
template <int K>
__global__ __launch_bounds__(256) void k_gemm(const float* __restrict__ X,
                                              const float* __restrict__ W,
                                              const float* __restrict__ scale,
                                              float* __restrict__ Y, int nrows) {
  constexpr int KC = 32;
  constexpr int NCH = K / KC;
  __shared__ __align__(16) float Xs[2][64][KC];
  __shared__ __align__(16) float Ws[2][KC][64];
  int t = threadIdx.x;
  int rbase = blockIdx.x * 64;
  int wid = t >> 6, l = t & 63;
  int p0 = wid * 2, p1 = p0 + 1;  // this wave's two 1KB pieces

  // piece p, lane l covers LDS floats [p*256 + l*4 .. +3] of an 8KB buffer.
  // X: row = p*8 + (l>>3), c4dest = l&7; source chunk = c4dest ^ (row&7).
  int xrow0 = p0 * 8 + (l >> 3);
  int xrow1 = p1 * 8 + (l >> 3);
  int gr0 = rbase + xrow0;
  int gr1 = rbase + xrow1;
  if (gr0 >= nrows) gr0 = nrows - 1;
  if (gr1 >= nrows) gr1 = nrows - 1;
  const float* xg0 = X + (size_t)gr0 * K + (((l & 7) ^ (xrow0 & 7)) << 2);
  const float* xg1 = X + (size_t)gr1 * K + (((l & 7) ^ (xrow1 & 7)) << 2);
  // W: row-in-chunk = p*4 + (l>>4), col = (l&15)*4; linear both sides.
  const float* wg0 = W + (size_t)(p0 * 4 + (l >> 4)) * 64 + ((l & 15) << 2);
  const float* wg1 = W + (size_t)(p1 * 4 + (l >> 4)) * 64 + ((l & 15) << 2);

#define STAGE(b, c)                                                   \
  do {                                                                \
    async16(xg0 + (c)*KC, (char*)&Xs[b][0][0] + p0 * 1024);           \
    async16(xg1 + (c)*KC, (char*)&Xs[b][0][0] + p1 * 1024);           \
    async16(wg0 + (size_t)(c)*KC * 64, (char*)&Ws[b][0][0] + p0 * 1024); \
    async16(wg1 + (size_t)(c)*KC * 64, (char*)&Ws[b][0][0] + p1 * 1024); \
  } while (0)

  STAGE(0, 0);
  asm volatile("s_waitcnt vmcnt(0)" ::: "memory");
  __syncthreads();

  int tx = t & 15, ty = t >> 4;
  int r0 = ty * 4, c0 = tx * 4;
  float acc[4][4] = {};

  for (int c = 0; c < NCH; ++c) {
    int cur = c & 1;
    if (c + 1 < NCH) STAGE(cur ^ 1, c + 1);
#pragma unroll
    for (int k = 0; k < KC; k += 4) {
      float xv[4][4], wv[4][4];
#pragma unroll
      for (int i = 0; i < 4; ++i) {
        int r = r0 + i;
        *(float4*)xv[i] = *(const float4*)&Xs[cur][r][(((k >> 2) ^ (r & 7))) << 2];
      }
#pragma unroll
      for (int j = 0; j < 4; ++j)
        *(float4*)wv[j] = *(const float4*)&Ws[cur][k + j][c0];
#pragma unroll
      for (int i = 0; i < 4; ++i)
#pragma unroll
        for (int kk = 0; kk < 4; ++kk)
#pragma unroll
          for (int j = 0; j < 4; ++j)
            acc[i][j] = fmaf(xv[i][kk], wv[kk][j], acc[i][j]);
    }
    if (c + 1 < NCH) {
      asm volatile("s_waitcnt vmcnt(0)" ::: "memory");
      __syncthreads();
    }
  }
#undef STAGE

#pragma unroll
  for (int i = 0; i < 4; ++i) {
    int gr = rbase + r0 + i;
    if (gr < nrows) {
      float sc = scale[gr];
      float4 o;
      o.x = acc[i][0] * sc;
      o.y = acc[i][1] * sc;
      o.z = acc[i][2] * sc;
      o.w = acc[i][3] * sc;
      *(float4*)(Y + (size_t)gr * 64 + c0) = o;
    }
  }
}

// Layer-0 aggregation over prescaled rows h1p (= h1 * dis1), fused with +b1,
// LayerNorm, ReLU, score s[v], block min/max partials.
__global__ __launch_bounds__(256) void k_agg1(
    const float* __restrict__ h1p, const int* __restrict__ offs,
    const int* __restrict__ indeg, const int* __restrict__ csr_src,
    const float* __restrict__ dis1, const float* __restrict__ b1,
    const float* __restrict__ gamma, const float* __restrict__ beta,
    float* __restrict__ h, float* __restrict__ s, float* __restrict__ mmpart) {
  int lane = threadIdx.x & 63;
  int wid = blockIdx.x * 4 + (threadIdx.x >> 6);
  int nw = gridDim.x * 4;
  float bmin = __builtin_inff(), bmax = -__builtin_inff();
  for (int v = wid; v < N_NODES; v += nw) {
    int beg = offs[v];
    int deg = indeg[v];
    float disv = dis1[v];
    float acc = h1p[v * 64 + lane];  // self-loop term (prescaled)
    for (int c = 0; c < deg; c += 64) {
      int m = deg - c;
      if (m > 64) m = 64;
      int ul = (lane < m) ? csr_src[beg + c + lane] : 0;
      int j = 0;
      for (; j + 8 <= m; j += 8) {
        int u0 = __shfl(ul, j + 0), u1 = __shfl(ul, j + 1);
        int u2 = __shfl(ul, j + 2), u3 = __shfl(ul, j + 3);
        int u4 = __shfl(ul, j + 4), u5 = __shfl(ul, j + 5);
        int u6 = __shfl(ul, j + 6), u7 = __shfl(ul, j + 7);
        float a0 = h1p[u0 * 64 + lane], a1 = h1p[u1 * 64 + lane];
        float a2 = h1p[u2 * 64 + lane], a3 = h1p[u3 * 64 + lane];
        float a4 = h1p[u4 * 64 + lane], a5 = h1p[u5 * 64 + lane];
        float a6 = h1p[u6 * 64 + lane], a7 = h1p[u7 * 64 + lane];
        acc += ((a0 + a1) + (a2 + a3)) + ((a4 + a5) + (a6 + a7));
      }
      for (; j < m; ++j) {
        int u = __shfl(ul, j);
        acc += h1p[u * 64 + lane];
      }
    }
    acc = disv * acc + b1[lane];
    float mu = wave_sum(acc) * (1.f / 64.f);
    float d = acc - mu;
    float var = wave_sum(d * d) * (1.f / 64.f);
    float hn = d * rsqrtf(var + LN_EPS) * gamma[lane] + beta[lane];
    hn = fmaxf(hn, 0.f);
    h[v * 64 + lane] = hn;
    float sv = sqrtf(wave_sum(hn * hn));  // wave-uniform
    if (lane == 0) s[v] = sv;
    bmin = fminf(bmin, sv);
    bmax = fmaxf(bmax, sv);
  }
  __shared__ float lmin[4], lmax[4];
  if ((threadIdx.x & 63) == 0) {
    lmin[threadIdx.x >> 6] = bmin;
    lmax[threadIdx.x >> 6] = bmax;
  }
  __syncthreads();
  if (threadIdx.x == 0) {
    mmpart[blockIdx.x * 2] = fminf(fminf(lmin[0], lmin[1]), fminf(lmin[2], lmin[3]));
    mmpart[blockIdx.x * 2 + 1] = fmaxf(fmaxf(lmax[0], lmax[1]), fmaxf(lmax[2], lmax[3]));
  }
}

__global__ void k_minmax2(const float* __restrict__ mmpart, float* __restrict__ smm,
                          int nblk) {
  int t = threadIdx.x;  // 256
  float mn = __builtin_inff(), mx = -__builtin_inff();
  for (int i = t; i < nblk; i += 256) {
    mn = fminf(mn, mmpart[i * 2]);
    mx = fmaxf(mx, mmpart[i * 2 + 1]);
  }
  for (int o = 32; o; o >>= 1) {
    mn = fminf(mn, __shfl_xor(mn, o, 64));
    mx = fmaxf(mx, __shfl_xor(mx, o, 64));
  }
  __shared__ float a[4], b[4];
  if ((t & 63) == 0) { a[t >> 6] = mn; b[t >> 6] = mx; }
  __syncthreads();
  if (t == 0) {
    smm[0] = fminf(fminf(a[0], a[1]), fminf(a[2], a[3]));
    smm[1] = fmaxf(fmaxf(b[0], b[1]), fmaxf(b[2], b[3]));
  }
}

__global__ void k_dis2(const float* __restrict__ s, const float* __restrict__ smm,
                       const int* __restrict__ indeg, float* __restrict__ dis2) {
  int v = blockIdx.x * blockDim.x + threadIdx.x;
  if (v < N_NODES) {
    float inv = 1.f / (smm[1] - smm[0] + 1e-8f);
    float sn = (s[v] - smm[0]) * inv;
    float d = (sn > THRV) ? (float)indeg[v] : 0.f;
    dis2[v] = rsqrtf(d + 1.f);
  }
}

// Layer-1 masked aggregation over prescaled rows h2p (= h2 * dis2), fused with
// +b2 and log_softmax into d_out.
__global__ __launch_bounds__(256) void k_agg2(
    const float* __restrict__ h2p, const int* __restrict__ offs,
    const int* __restrict__ indeg, const int* __restrict__ csr_src,
    const float* __restrict__ s, const float* __restrict__ smm,
    const float* __restrict__ dis2, const float* __restrict__ b2,
    float* __restrict__ out) {
  int lane = threadIdx.x & 63;
  int wid = blockIdx.x * 4 + (threadIdx.x >> 6);
  int nw = gridDim.x * 4;
  float smin = smm[0];
  float inv = 1.f / (smm[1] - smm[0] + 1e-8f);
  for (int v = wid; v < N_NODES; v += nw) {
    float disv = dis2[v];
    float sn = (s[v] - smin) * inv;
    float acc = h2p[v * 64 + lane];  // self-loop term (prescaled)
    if (sn > THRV) {
      int beg = offs[v];
      int deg = indeg[v];
      for (int c = 0; c < deg; c += 64) {
        int m = deg - c;
        if (m > 64) m = 64;
        int ul = (lane < m) ? csr_src[beg + c + lane] : 0;
        int j = 0;
        for (; j + 8 <= m; j += 8) {
          int u0 = __shfl(ul, j + 0), u1 = __shfl(ul, j + 1);
          int u2 = __shfl(ul, j + 2), u3 = __shfl(ul, j + 3);
          int u4 = __shfl(ul, j + 4), u5 = __shfl(ul, j + 5);
          int u6 = __shfl(ul, j + 6), u7 = __shfl(ul, j + 7);
          float a0 = h2p[u0 * 64 + lane], a1 = h2p[u1 * 64 + lane];
          float a2 = h2p[u2 * 64 + lane], a3 = h2p[u3 * 64 + lane];
          float a4 = h2p[u4 * 64 + lane], a5 = h2p[u5 * 64 + lane];
          float a6 = h2p[u6 * 64 + lane], a7 = h2p[u7 * 64 + lane];
          acc += ((a0 + a1) + (a2 + a3)) + ((a4 + a5) + (a6 + a7));
        }
        for (; j < m; ++j) {
          int u = __shfl(ul, j);
          acc += h2p[u * 64 + lane];
        }
      }
    }
    acc = disv * acc + b2[lane];
    float m = wave_max(acc);
    float p = expf(acc - m);
    float sum = wave_sum(p);
    out[v * 64 + lane] = acc - m - logf(sum);
  }
}

extern "C" void kernel_launch(void* const* d_in, const int* in_sizes, int n_in,
                              void* d_out, int out_size, void* d_ws, size_t ws_size,
                              hipStream_t stream) {
  const float* x = (const float*)d_in[0];
  const float* W1 = (const float*)d_in[1];
  const float* b1 = (const float*)d_in[2];
  const float* W2 = (const float*)d_in[3];
  const float* b2 = (const float*)d_in[4];
  const float* gamma = (const float*)d_in[5];
  const float* beta = (const float*)d_in[6];
  const int* ei = (const int*)d_in[7];
  const int* src = ei;
  const int* dst = ei + N_EDGES;
  float* out = (float*)d_out;

  char* ws = (char*)d_ws;
  size_t off = 0;
  auto alloc = [&](size_t bytes) {
    void* p = ws + off;
    off += (bytes + 255) & ~(size_t)255;
    return p;
  };
  int* indeg = (int*)alloc(N_NODES * 4);
  int* offs = (int*)alloc(N_NODES * 4);
  int* bcnt = (int*)alloc(NB * 4);
  int* bbase = (int*)alloc((NB + 1) * 4);
  int* bcur = (int*)alloc(NB * 4);
  int* csr_src = (int*)alloc(N_EDGES * 4);
  float* s = (float*)alloc(N_NODES * 4);
  float* dis1 = (float*)alloc(N_NODES * 4);
  float* dis2 = (float*)alloc(N_NODES * 4);
  float* mmpart = (float*)alloc(GRID_AGG * 2 * 4);
  float* smm = (float*)alloc(256);
  float* h1 = (float*)alloc((size_t)N_NODES * 64 * 4);
  float* h = (float*)alloc((size_t)N_NODES * 64 * 4);
  int* part = (int*)h1;  // alias: part is dead before gemm1 writes h1
  (void)ws_size;
  (void)n_in;
  (void)in_sizes;
  (void)out_size;

  hipMemsetAsync(bcnt, 0, NB * 4, stream);
  k_bcount<<<NPB, 256, 0, stream>>>(dst, bcnt);
  k_bscan<<<1, 256, 0, stream>>>(bcnt, bbase, bcur);
  k_part<<<NPB, 256, 0, stream>>>(src, dst, bcur, part);
  k_build<<<NB, 256, 0, stream>>>(part, bbase, indeg, offs, dis1, csr_src);
  int gemm_grid = (N_NODES + 63) / 64;  // 1563
  k_gemm<IN_F><<<gemm_grid, 256, 0, stream>>>(x, W1, dis1, h1, N_NODES);
  k_agg1<<<GRID_AGG, 256, 0, stream>>>(h1, offs, indeg, csr_src, dis1, b1, gamma,
                                       beta, h, s, mmpart);
  k_minmax2<<<1, 256, 0, stream>>>(mmpart, smm, GRID_AGG);
  k_dis2<<<(N_NODES + 255) / 256, 256, 0, stream>>>(s, smm, indeg, dis2);
  k_gemm<H_F><<<gemm_grid, 256, 0, stream>>>(h, W2, dis2, h1 /* reuse as h2p */, N_NODES);
  k_agg2<<<GRID_AGG, 256, 0, stream>>>(h1, offs, indeg, csr_src, s, smm, dis2, b2,
                                       out);
}

// Round 7
// 227.115 us; speedup vs baseline: 8.1453x; 1.0523x over previous
//
#include <hip/hip_runtime.h>
#include <math.h>

#define N_NODES 100000
#define N_EDGES 1000000
#define IN_F 128
#define H_F 64
#define THRV 0.1f
#define LN_EPS 1e-5f
#define GRID_AGG 2048

#define BSHIFT 9                 // 512 nodes per bucket
#define NB 196                   // ceil(100000 / 512)
#define EPB 2048                 // edges per partition block
#define NPB ((N_EDGES + EPB - 1) / EPB)  // 489

static __device__ __forceinline__ float wave_sum(float x) {
  for (int o = 32; o > 0; o >>= 1) x += __shfl_xor(x, o, 64);
  return x;
}
static __device__ __forceinline__ float wave_max(float x) {
  for (int o = 32; o > 0; o >>= 1) x = fmaxf(x, __shfl_xor(x, o, 64));
  return x;
}

// ---- CSR build via bucket partition (no random global scatter) ----

__global__ __launch_bounds__(256) void k_bcount(const int* __restrict__ dst,
                                                int* __restrict__ bcnt) {
  __shared__ int h[NB];
  for (int i = threadIdx.x; i < NB; i += 256) h[i] = 0;
  __syncthreads();
  int base = blockIdx.x * EPB;
  for (int i = threadIdx.x; i < EPB; i += 256) {
    int e = base + i;
    if (e < N_EDGES) atomicAdd(&h[dst[e] >> BSHIFT], 1);
  }
  __syncthreads();
  for (int i = threadIdx.x; i < NB; i += 256)
    if (h[i]) atomicAdd(&bcnt[i], h[i]);
}

__global__ void k_bscan(const int* __restrict__ bcnt, int* __restrict__ bbase,
                        int* __restrict__ bcur) {
  __shared__ int lds[256];
  int t = threadIdx.x;
  int v = (t < NB) ? bcnt[t] : 0;
  lds[t] = v;
  __syncthreads();
  int val = v;
  for (int o = 1; o < 256; o <<= 1) {
    int y = (t >= o) ? lds[t - o] : 0;
    __syncthreads();
    val += y;
    lds[t] = val;
    __syncthreads();
  }
  if (t < NB) {
    int ex = val - v;
    bbase[t] = ex;
    bcur[t] = ex;
  }
  if (t == 255) bbase[NB] = val;  // total
}

// Partition edges into bucket-contiguous regions as packed records:
// rec = src | (dstLocal << 17)   (src < 2^17, dstLocal < 2^9)
__global__ __launch_bounds__(256) void k_part(const int* __restrict__ src,
                                              const int* __restrict__ dst,
                                              int* __restrict__ bcur,
                                              int* __restrict__ part) {
  __shared__ int h[NB];
  __shared__ int cur[NB];
  for (int i = threadIdx.x; i < NB; i += 256) h[i] = 0;
  __syncthreads();
  int base = blockIdx.x * EPB;
  for (int i = threadIdx.x; i < EPB; i += 256) {
    int e = base + i;
    if (e < N_EDGES) atomicAdd(&h[dst[e] >> BSHIFT], 1);
  }
  __syncthreads();
  for (int i = threadIdx.x; i < NB; i += 256) {
    int c = h[i];
    cur[i] = c ? atomicAdd(&bcur[i], c) : 0;
  }
  __syncthreads();
  for (int i = threadIdx.x; i < EPB; i += 256) {
    int e = base + i;
    if (e < N_EDGES) {
      int d = dst[e];
      int b = d >> BSHIFT;
      int pos = atomicAdd(&cur[b], 1);
      part[pos] = src[e] | ((d & 511) << 17);
    }
  }
}

// One block per bucket: count per-node degrees in LDS, scan, emit
// indeg/offs/dis1 (coalesced) and csr_src (scatter within L2-resident region).
__global__ __launch_bounds__(256) void k_build(
    const int* __restrict__ part, const int* __restrict__ bbase,
    int* __restrict__ indeg, int* __restrict__ offs, float* __restrict__ dis1,
    int* __restrict__ csr_src) {
  __shared__ int cnt[512];
  __shared__ int slds[256];
  int b = blockIdx.x;
  int t = threadIdx.x;
  int beg = bbase[b], end = bbase[b + 1];
  for (int i = t; i < 512; i += 256) cnt[i] = 0;
  __syncthreads();
  for (int i = beg + t; i < end; i += 256)
    atomicAdd(&cnt[(part[i] >> 17) & 511], 1);
  __syncthreads();
  int a0 = cnt[2 * t], a1 = cnt[2 * t + 1];
  int pairsum = a0 + a1;
  slds[t] = pairsum;
  __syncthreads();
  int val = pairsum;
  for (int o = 1; o < 256; o <<= 1) {
    int y = (t >= o) ? slds[t - o] : 0;
    __syncthreads();
    val += y;
    slds[t] = val;
    __syncthreads();
  }
  int ex = val - pairsum;  // exclusive over this thread's pair
  int off0 = ex, off1 = ex + a0;
  cnt[2 * t] = off0;  // reuse as scatter cursors
  cnt[2 * t + 1] = off1;
  int node0 = (b << BSHIFT) + 2 * t;
  if (node0 < N_NODES) {
    indeg[node0] = a0;
    offs[node0] = beg + off0;
    dis1[node0] = rsqrtf((float)a0 + 1.f);
  }
  if (node0 + 1 < N_NODES) {
    indeg[node0 + 1] = a1;
    offs[node0 + 1] = beg + off1;
    dis1[node0 + 1] = rsqrtf((float)a1 + 1.f);
  }
  __syncthreads();
  for (int i = beg + t; i < end; i += 256) {
    int p = part[i];
    int loc = (p >> 17) & 511;
    int pos = atomicAdd(&cnt[loc], 1);
    csr_src[beg + pos] = p & 131071;
  }
}

// Wave-autonomous W-stationary GEMM: Y[r][64] = (X[r][K] @ W[K][64]) * scale[r].
// Only W is staged in LDS (once, one barrier, then read-only -> NO barriers in
// the K loop; waves run independently and the compiler software-pipelines the
// X loads). Each wave owns 16 rows: lane = (ty row-group of 4 rows) x (tx 4
// cols). X fragments broadcast-load from global (16 lanes share each 16B;
// lines reused across 4 consecutive k-steps via L1). W reads are row-wide
// (2-way bank conflict = free).
template <int K>
__global__ __launch_bounds__(256) void k_gemm(const float* __restrict__ X,
                                              const float* __restrict__ W,
                                              const float* __restrict__ scale,
                                              float* __restrict__ Y, int nrows) {
  __shared__ __align__(16) float Ws[K][64];
  int t = threadIdx.x;
  for (int idx = t; idx < K * 16; idx += 256)
    ((float4*)&Ws[0][0])[idx] = ((const float4*)W)[idx];
  __syncthreads();

  int lane = t & 63;
  int wid = t >> 6;
  int tx = lane & 15, ty = lane >> 4;
  int rbase = blockIdx.x * 64 + wid * 16 + ty * 4;
  int r[4];
#pragma unroll
  for (int i = 0; i < 4; ++i) {
    int g = rbase + i;
    r[i] = (g < nrows) ? g : (nrows - 1);
  }
  int c0 = tx * 4;
  float acc[4][4] = {};

#pragma unroll 2
  for (int k = 0; k < K; k += 4) {
    float xv[4][4], wv[4][4];
#pragma unroll
    for (int i = 0; i < 4; ++i)
      *(float4*)xv[i] = *(const float4*)(X + (size_t)r[i] * K + k);
#pragma unroll
    for (int j = 0; j < 4; ++j)
      *(float4*)wv[j] = *(const float4*)&Ws[k + j][c0];
#pragma unroll
    for (int i = 0; i < 4; ++i)
#pragma unroll
      for (int kk = 0; kk < 4; ++kk)
#pragma unroll
        for (int j = 0; j < 4; ++j)
          acc[i][j] = fmaf(xv[i][kk], wv[kk][j], acc[i][j]);
  }

#pragma unroll
  for (int i = 0; i < 4; ++i) {
    int gr = rbase + i;
    if (gr < nrows) {
      float sc = scale[gr];
      float4 o;
      o.x = acc[i][0] * sc;
      o.y = acc[i][1] * sc;
      o.z = acc[i][2] * sc;
      o.w = acc[i][3] * sc;
      *(float4*)(Y + (size_t)gr * 64 + c0) = o;
    }
  }
}

// Layer-0 aggregation over prescaled rows h1p (= h1 * dis1), fused with +b1,
// LayerNorm, ReLU, score s[v], block min/max partials.
__global__ __launch_bounds__(256) void k_agg1(
    const float* __restrict__ h1p, const int* __restrict__ offs,
    const int* __restrict__ indeg, const int* __restrict__ csr_src,
    const float* __restrict__ dis1, const float* __restrict__ b1,
    const float* __restrict__ gamma, const float* __restrict__ beta,
    float* __restrict__ h, float* __restrict__ s, float* __restrict__ mmpart) {
  int lane = threadIdx.x & 63;
  int wid = blockIdx.x * 4 + (threadIdx.x >> 6);
  int nw = gridDim.x * 4;
  float bmin = __builtin_inff(), bmax = -__builtin_inff();
  for (int v = wid; v < N_NODES; v += nw) {
    int beg = offs[v];
    int deg = indeg[v];
    float disv = dis1[v];
    float acc = h1p[v * 64 + lane];  // self-loop term (prescaled)
    for (int c = 0; c < deg; c += 64) {
      int m = deg - c;
      if (m > 64) m = 64;
      int ul = (lane < m) ? csr_src[beg + c + lane] : 0;
      int j = 0;
      for (; j + 8 <= m; j += 8) {
        int u0 = __shfl(ul, j + 0), u1 = __shfl(ul, j + 1);
        int u2 = __shfl(ul, j + 2), u3 = __shfl(ul, j + 3);
        int u4 = __shfl(ul, j + 4), u5 = __shfl(ul, j + 5);
        int u6 = __shfl(ul, j + 6), u7 = __shfl(ul, j + 7);
        float a0 = h1p[u0 * 64 + lane], a1 = h1p[u1 * 64 + lane];
        float a2 = h1p[u2 * 64 + lane], a3 = h1p[u3 * 64 + lane];
        float a4 = h1p[u4 * 64 + lane], a5 = h1p[u5 * 64 + lane];
        float a6 = h1p[u6 * 64 + lane], a7 = h1p[u7 * 64 + lane];
        acc += ((a0 + a1) + (a2 + a3)) + ((a4 + a5) + (a6 + a7));
      }
      for (; j < m; ++j) {
        int u = __shfl(ul, j);
        acc += h1p[u * 64 + lane];
      }
    }
    acc = disv * acc + b1[lane];
    float mu = wave_sum(acc) * (1.f / 64.f);
    float d = acc - mu;
    float var = wave_sum(d * d) * (1.f / 64.f);
    float hn = d * rsqrtf(var + LN_EPS) * gamma[lane] + beta[lane];
    hn = fmaxf(hn, 0.f);
    h[v * 64 + lane] = hn;
    float sv = sqrtf(wave_sum(hn * hn));  // wave-uniform
    if (lane == 0) s[v] = sv;
    bmin = fminf(bmin, sv);
    bmax = fmaxf(bmax, sv);
  }
  __shared__ float lmin[4], lmax[4];
  if ((threadIdx.x & 63) == 0) {
    lmin[threadIdx.x >> 6] = bmin;
    lmax[threadIdx.x >> 6] = bmax;
  }
  __syncthreads();
  if (threadIdx.x == 0) {
    mmpart[blockIdx.x * 2] = fminf(fminf(lmin[0], lmin[1]), fminf(lmin[2], lmin[3]));
    mmpart[blockIdx.x * 2 + 1] = fmaxf(fmaxf(lmax[0], lmax[1]), fmaxf(lmax[2], lmax[3]));
  }
}

__global__ void k_minmax2(const float* __restrict__ mmpart, float* __restrict__ smm,
                          int nblk) {
  int t = threadIdx.x;  // 256
  float mn = __builtin_inff(), mx = -__builtin_inff();
  for (int i = t; i < nblk; i += 256) {
    mn = fminf(mn, mmpart[i * 2]);
    mx = fmaxf(mx, mmpart[i * 2 + 1]);
  }
  for (int o = 32; o; o >>= 1) {
    mn = fminf(mn, __shfl_xor(mn, o, 64));
    mx = fmaxf(mx, __shfl_xor(mx, o, 64));
  }
  __shared__ float a[4], b[4];
  if ((t & 63) == 0) { a[t >> 6] = mn; b[t >> 6] = mx; }
  __syncthreads();
  if (t == 0) {
    smm[0] = fminf(fminf(a[0], a[1]), fminf(a[2], a[3]));
    smm[1] = fmaxf(fmaxf(b[0], b[1]), fmaxf(b[2], b[3]));
  }
}

__global__ void k_dis2(const float* __restrict__ s, const float* __restrict__ smm,
                       const int* __restrict__ indeg, float* __restrict__ dis2) {
  int v = blockIdx.x * blockDim.x + threadIdx.x;
  if (v < N_NODES) {
    float inv = 1.f / (smm[1] - smm[0] + 1e-8f);
    float sn = (s[v] - smm[0]) * inv;
    float d = (sn > THRV) ? (float)indeg[v] : 0.f;
    dis2[v] = rsqrtf(d + 1.f);
  }
}

// Layer-1 masked aggregation over prescaled rows h2p (= h2 * dis2), fused with
// +b2 and log_softmax into d_out.
__global__ __launch_bounds__(256) void k_agg2(
    const float* __restrict__ h2p, const int* __restrict__ offs,
    const int* __restrict__ indeg, const int* __restrict__ csr_src,
    const float* __restrict__ s, const float* __restrict__ smm,
    const float* __restrict__ dis2, const float* __restrict__ b2,
    float* __restrict__ out) {
  int lane = threadIdx.x & 63;
  int wid = blockIdx.x * 4 + (threadIdx.x >> 6);
  int nw = gridDim.x * 4;
  float smin = smm[0];
  float inv = 1.f / (smm[1] - smm[0] + 1e-8f);
  for (int v = wid; v < N_NODES; v += nw) {
    float disv = dis2[v];
    float sn = (s[v] - smin) * inv;
    float acc = h2p[v * 64 + lane];  // self-loop term (prescaled)
    if (sn > THRV) {
      int beg = offs[v];
      int deg = indeg[v];
      for (int c = 0; c < deg; c += 64) {
        int m = deg - c;
        if (m > 64) m = 64;
        int ul = (lane < m) ? csr_src[beg + c + lane] : 0;
        int j = 0;
        for (; j + 8 <= m; j += 8) {
          int u0 = __shfl(ul, j + 0), u1 = __shfl(ul, j + 1);
          int u2 = __shfl(ul, j + 2), u3 = __shfl(ul, j + 3);
          int u4 = __shfl(ul, j + 4), u5 = __shfl(ul, j + 5);
          int u6 = __shfl(ul, j + 6), u7 = __shfl(ul, j + 7);
          float a0 = h2p[u0 * 64 + lane], a1 = h2p[u1 * 64 + lane];
          float a2 = h2p[u2 * 64 + lane], a3 = h2p[u3 * 64 + lane];
          float a4 = h2p[u4 * 64 + lane], a5 = h2p[u5 * 64 + lane];
          float a6 = h2p[u6 * 64 + lane], a7 = h2p[u7 * 64 + lane];
          acc += ((a0 + a1) + (a2 + a3)) + ((a4 + a5) + (a6 + a7));
        }
        for (; j < m; ++j) {
          int u = __shfl(ul, j);
          acc += h2p[u * 64 + lane];
        }
      }
    }
    acc = disv * acc + b2[lane];
    float m = wave_max(acc);
    float p = expf(acc - m);
    float sum = wave_sum(p);
    out[v * 64 + lane] = acc - m - logf(sum);
  }
}

extern "C" void kernel_launch(void* const* d_in, const int* in_sizes, int n_in,
                              void* d_out, int out_size, void* d_ws, size_t ws_size,
                              hipStream_t stream) {
  const float* x = (const float*)d_in[0];
  const float* W1 = (const float*)d_in[1];
  const float* b1 = (const float*)d_in[2];
  const float* W2 = (const float*)d_in[3];
  const float* b2 = (const float*)d_in[4];
  const float* gamma = (const float*)d_in[5];
  const float* beta = (const float*)d_in[6];
  const int* ei = (const int*)d_in[7];
  const int* src = ei;
  const int* dst = ei + N_EDGES;
  float* out = (float*)d_out;

  char* ws = (char*)d_ws;
  size_t off = 0;
  auto alloc = [&](size_t bytes) {
    void* p = ws + off;
    off += (bytes + 255) & ~(size_t)255;
    return p;
  };
  int* indeg = (int*)alloc(N_NODES * 4);
  int* offs = (int*)alloc(N_NODES * 4);
  int* bcnt = (int*)alloc(NB * 4);
  int* bbase = (int*)alloc((NB + 1) * 4);
  int* bcur = (int*)alloc(NB * 4);
  int* csr_src = (int*)alloc(N_EDGES * 4);
  float* s = (float*)alloc(N_NODES * 4);
  float* dis1 = (float*)alloc(N_NODES * 4);
  float* dis2 = (float*)alloc(N_NODES * 4);
  float* mmpart = (float*)alloc(GRID_AGG * 2 * 4);
  float* smm = (float*)alloc(256);
  float* h1 = (float*)alloc((size_t)N_NODES * 64 * 4);
  float* h = (float*)alloc((size_t)N_NODES * 64 * 4);
  int* part = (int*)h1;  // alias: part is dead before gemm1 writes h1
  (void)ws_size;
  (void)n_in;
  (void)in_sizes;
  (void)out_size;

  hipMemsetAsync(bcnt, 0, NB * 4, stream);
  k_bcount<<<NPB, 256, 0, stream>>>(dst, bcnt);
  k_bscan<<<1, 256, 0, stream>>>(bcnt, bbase, bcur);
  k_part<<<NPB, 256, 0, stream>>>(src, dst, bcur, part);
  k_build<<<NB, 256, 0, stream>>>(part, bbase, indeg, offs, dis1, csr_src);
  int gemm_grid = (N_NODES + 63) / 64;  // 1563
  k_gemm<IN_F><<<gemm_grid, 256, 0, stream>>>(x, W1, dis1, h1, N_NODES);
  k_agg1<<<GRID_AGG, 256, 0, stream>>>(h1, offs, indeg, csr_src, dis1, b1, gamma,
                                       beta, h, s, mmpart);
  k_minmax2<<<1, 256, 0, stream>>>(mmpart, smm, GRID_AGG);
  k_dis2<<<(N_NODES + 255) / 256, 256, 0, stream>>>(s, smm, indeg, dis2);
  k_gemm<H_F><<<gemm_grid, 256, 0, stream>>>(h, W2, dis2, h1 /* reuse as h2p */, N_NODES);
  k_agg2<<<GRID_AGG, 256, 0, stream>>>(h1, offs, indeg, csr_src, s, smm, dis2, b2,
                                       out);
}